// Round 7
// baseline (852.092 us; speedup 1.0000x reference)
//
#include <hip/hip_runtime.h>
#include <math.h>

#define BATCH  2
#define SEQ    2048
#define NHEAD  16
#define DMODEL 2048
#define DCKV   512
#define DCQ    1024
#define DHEAD  128
#define DROPE  64

typedef unsigned short u16;
typedef __attribute__((ext_vector_type(8))) short bf16x8;
typedef __attribute__((ext_vector_type(4))) float f32x4;

__device__ __forceinline__ u16 f2bf(float f) {           // RNE
    union { float f; unsigned u; } v; v.f = f;
    unsigned r = v.u + 0x7FFFu + ((v.u >> 16) & 1u);
    return (u16)(r >> 16);
}
__device__ __forceinline__ float bf2f(u16 h) {
    union { unsigned u; float f; } v; v.u = ((unsigned)h) << 16;
    return v.f;
}

// async global->LDS, 16B per lane; lds dest must be wave-uniform base (+lane*16)
__device__ __forceinline__ void gload_lds16(const u16* g, u16* l) {
    typedef const __attribute__((address_space(1))) u16* gp_t;
    typedef __attribute__((address_space(3))) u16* lp_t;
    __builtin_amdgcn_global_load_lds((gp_t)g, (lp_t)l, 16, 0, 0);
}

// ---------------------------------------------------------------------------
// flat f32 -> bf16 convert (n multiple of 4)
// ---------------------------------------------------------------------------
__global__ __launch_bounds__(256) void convert_bf16(const float* __restrict__ in,
                                                    u16* __restrict__ out, int n)
{
    int i = (blockIdx.x * 256 + threadIdx.x) * 4;
    if (i >= n) return;
    float4 v = *(const float4*)&in[i];
    union { u16 u[4]; uint2 w; } o;
    o.u[0] = f2bf(v.x); o.u[1] = f2bf(v.y); o.u[2] = f2bf(v.z); o.u[3] = f2bf(v.w);
    *(uint2*)&out[i] = o.w;
}

// ---------------------------------------------------------------------------
// transpose+convert: in f32 [R][C] -> out bf16 [C][R] (ldout = R).
// R,C multiples of 64.  grid (C/64, R/64).
// ---------------------------------------------------------------------------
__global__ __launch_bounds__(256) void transpose_f32_bf16(const float* __restrict__ in,
                                                          u16* __restrict__ out,
                                                          int R, int C)
{
    __shared__ u16 t[64][70];
    const int r0 = blockIdx.y * 64, c0 = blockIdx.x * 64;
    const int tid = threadIdx.x;
#pragma unroll
    for (int i = 0; i < 4; ++i) {
        int c = tid + i * 256;           // 0..1023
        int r = c >> 4, q = (c & 15) * 4;
        float4 v = *(const float4*)&in[(size_t)(r0 + r) * C + c0 + q];
        t[r][q + 0] = f2bf(v.x); t[r][q + 1] = f2bf(v.y);
        t[r][q + 2] = f2bf(v.z); t[r][q + 3] = f2bf(v.w);
    }
    __syncthreads();
#pragma unroll
    for (int i = 0; i < 2; ++i) {
        int c = tid + i * 256;           // 0..511
        int orow = c >> 3, os = (c & 7) * 8;
        union { u16 u[8]; uint4 w; } o;
#pragma unroll
        for (int j = 0; j < 8; ++j) o.u[j] = t[os + j][orow];
        *(uint4*)&out[(size_t)(c0 + orow) * R + r0 + os] = o.w;
    }
}

// ---------------------------------------------------------------------------
// transpose bf16 [R][C] (row stride ldin) -> bf16 [C][R] contig, batched z.
// ---------------------------------------------------------------------------
__global__ __launch_bounds__(256) void transpose_b16(const u16* __restrict__ in,
                                                     u16* __restrict__ out,
                                                     int R, int C, int ldin,
                                                     size_t sIn, size_t sOut)
{
    __shared__ u16 t[64][72];
    const u16* inz = in + (size_t)blockIdx.z * sIn;
    u16* outz = out + (size_t)blockIdx.z * sOut;
    const int r0 = blockIdx.y * 64, c0 = blockIdx.x * 64;
    const int tid = threadIdx.x;
#pragma unroll
    for (int i = 0; i < 2; ++i) {
        int c = tid + i * 256;           // 0..511
        int r = c >> 3, q = (c & 7) * 8;
        union { u16 u[8]; uint4 w; } v;
        v.w = *(const uint4*)&inz[(size_t)(r0 + r) * ldin + c0 + q];
#pragma unroll
        for (int j = 0; j < 8; ++j) t[r][q + j] = v.u[j];
    }
    __syncthreads();
#pragma unroll
    for (int i = 0; i < 2; ++i) {
        int c = tid + i * 256;
        int orow = c >> 3, os = (c & 7) * 8;
        union { u16 u[8]; uint4 w; } o;
#pragma unroll
        for (int j = 0; j < 8; ++j) o.u[j] = t[os + j][orow];
        *(uint4*)&outz[(size_t)(c0 + orow) * R + r0 + os] = o.w;
    }
}

// ---------------------------------------------------------------------------
// bf16 MFMA GEMM with strides: C[M,N] = A[M,K] * Bt[N,K]^T, fp32 accum.
// A row stride lda, Bt row stride ldb, C row stride ldc (elements).
// 128x128 tile, BK=64, 256 thr = 4 waves (2x2), wave = 64x64 = 4x4 frags.
// Staging: global_load_lds x16, pre-swizzled per-lane SOURCE + linear LDS
// dest; frag reads apply the same involutive XOR (16B slot ^= row&7).
// M mult 128, N mult 128 (Bt rows >= N), K mult 64.  lda/ldb 8-elem aligned.
// ---------------------------------------------------------------------------
template<int OUTBF16>
__global__ __launch_bounds__(256) void gemm_bf16(const u16* __restrict__ A,
                                                 const u16* __restrict__ Bt,
                                                 void* __restrict__ C,
                                                 int M, int N, int K,
                                                 int lda, int ldb, int ldc)
{
    __shared__ __align__(16) u16 As[128 * 64];
    __shared__ __align__(16) u16 Bs[128 * 64];

    const int tid = threadIdx.x;
    const int m0 = blockIdx.y * 128;
    const int n0 = blockIdx.x * 128;
    const int lane = tid & 63;
    const int wid = tid >> 6;
    const int wm = (wid & 1) * 64;
    const int wn = (wid >> 1) * 64;
    const int lr = lane & 15;
    const int lk = lane >> 4;

    f32x4 acc[4][4];
#pragma unroll
    for (int i = 0; i < 4; ++i)
#pragma unroll
        for (int j = 0; j < 4; ++j) acc[i][j] = {0.f, 0.f, 0.f, 0.f};

    for (int kt = 0; kt < K; kt += 64) {
        __syncthreads();
        // ---- stage A,B: linear LDS dest, inverse-swizzled global source ---
#pragma unroll
        for (int i = 0; i < 4; ++i) {
            int d0 = (i * 4 + wid) * 64;
            int d = d0 + lane;
            int row = d >> 3, sl = d & 7;
            gload_lds16(&A[(size_t)(m0 + row) * lda + kt + ((sl ^ (row & 7)) << 3)], &As[d0 * 8]);
        }
#pragma unroll
        for (int i = 0; i < 4; ++i) {
            int d0 = (i * 4 + wid) * 64;
            int d = d0 + lane;
            int row = d >> 3, sl = d & 7;
            gload_lds16(&Bt[(size_t)(n0 + row) * ldb + kt + ((sl ^ (row & 7)) << 3)], &Bs[d0 * 8]);
        }
        __syncthreads();   // drains vmcnt before s_barrier

#pragma unroll
        for (int ks = 0; ks < 2; ++ks) {
            bf16x8 af[4], bfr[4];
#pragma unroll
            for (int mf = 0; mf < 4; ++mf) {
                int row = wm + mf * 16 + lr;
                int sl = (ks * 4 + lk) ^ (row & 7);
                af[mf] = *(const bf16x8*)&As[row * 64 + sl * 8];
            }
#pragma unroll
            for (int nf = 0; nf < 4; ++nf) {
                int row = wn + nf * 16 + lr;
                int sl = (ks * 4 + lk) ^ (row & 7);
                bfr[nf] = *(const bf16x8*)&Bs[row * 64 + sl * 8];
            }
#pragma unroll
            for (int mf = 0; mf < 4; ++mf)
#pragma unroll
                for (int nf = 0; nf < 4; ++nf)
                    acc[mf][nf] = __builtin_amdgcn_mfma_f32_16x16x32_bf16(
                        af[mf], bfr[nf], acc[mf][nf], 0, 0, 0);
        }
    }

    const int crow0 = m0 + wm + lk * 4;
    const int ccol0 = n0 + wn + lr;
#pragma unroll
    for (int mf = 0; mf < 4; ++mf)
#pragma unroll
        for (int nf = 0; nf < 4; ++nf) {
            int coln = ccol0 + nf * 16;
            if (coln < N) {
#pragma unroll
                for (int r = 0; r < 4; ++r) {
                    int rm = crow0 + mf * 16 + r;
                    float v = acc[mf][nf][r];
                    if (OUTBF16) ((u16*)C)[(size_t)rm * ldc + coln] = f2bf(v);
                    else         ((float*)C)[(size_t)rm * ldc + coln] = v;
                }
            }
        }
}

// ---------------------------------------------------------------------------
// pope: read bf16 [B*S rows, stride ldin] (hcols*64 wide), softplus+rotate,
// write bf16 [B*S rows, stride ldout].  pair (j, j+32) shares angle j.
// ---------------------------------------------------------------------------
__device__ __forceinline__ float softplusf(float v)
{
    if (v > 20.f) return v;
    return log1pf(__expf(v));
}

__global__ __launch_bounds__(256) void pope_b16(const u16* __restrict__ in, int ldin,
                                                u16* __restrict__ outb, int ldout,
                                                const float* __restrict__ delta,
                                                int hcols)
{
    const int idx = blockIdx.x * 256 + threadIdx.x;
    const int total = BATCH * SEQ * hcols * 32;
    if (idx >= total) return;
    const int j = idx & 31;
    const int h = (idx >> 5) % hcols;
    const int rowid = idx / (32 * hcols);
    const int s = rowid % SEQ;

    const float theta = __expf(-(2.0f * (float)j) * (9.210340371976184f / 64.0f));
    const float ang = (float)s * theta + delta[j];
    float sn, cs;
    sincosf(ang, &sn, &cs);

    const u16* row = in + (size_t)rowid * ldin + h * 64;
    u16* orow = outb + (size_t)rowid * ldout + h * 64;
    const float mu1 = softplusf(bf2f(row[j]));
    const float mu2 = softplusf(bf2f(row[j + 32]));
    orow[j]      = f2bf(mu1 * cs - mu2 * sn);
    orow[j + 32] = f2bf(mu1 * sn + mu2 * cs);
}

// ---------------------------------------------------------------------------
// MFMA flash attention (64-row q-tile, proven round-3 structure + P-alias).
// grid (SEQ/64, BATCH*NHEAD), 256 thr = 4 waves; wave w owns q-rows
// [w*16, w*16+16).  LDS: Ks 24KB (P aliased per-wave after 3rd barrier) +
// Vs 16KB = 40KB -> 4 blocks/CU; VGPR capped 128 -> 16 waves/CU.
// qc row stride qc_ld, kc row stride kc_ld; qr/kr/vt contiguous.
// ---------------------------------------------------------------------------
__global__ __launch_bounds__(256, 4) void attn_mfma(const u16* __restrict__ qc, int qc_ld,
                                                    const u16* __restrict__ qr,
                                                    const u16* __restrict__ kc, int kc_ld,
                                                    const u16* __restrict__ kr,
                                                    const u16* __restrict__ vt,
                                                    u16* __restrict__ ao)
{
    __shared__ __align__(16) u16 Ks[64 * 192];     // [key][24 slots]; P alias
    __shared__ __align__(16) u16 Vs[128 * 64];     // [d][8 slots]

    const int qi = gridDim.x - 1 - blockIdx.x;     // big blocks first
    const int q0 = qi * 64;
    const int bh = blockIdx.y;
    const int b = bh >> 4, h = bh & 15;
    const int tid = threadIdx.x, lane = tid & 63, wid = tid >> 6;
    const int lr = lane & 15, lk = lane >> 4;
    const float scale = 0.07216878364870323f;      // 1/sqrt(192)

    // Q fragments (A-operand rows = lane&15), hoisted
    bf16x8 qf[6];
    {
        const int sq = q0 + wid * 16 + lr;
        const size_t qb = ((size_t)(b * SEQ + sq)) * qc_ld + h * DHEAD;
        const size_t rb = ((size_t)(b * SEQ + sq)) * (NHEAD * DROPE) + h * DROPE;
#pragma unroll
        for (int ks = 0; ks < 4; ++ks) qf[ks] = *(const bf16x8*)&qc[qb + ks * 32 + lk * 8];
#pragma unroll
        for (int ks = 4; ks < 6; ++ks) qf[ks] = *(const bf16x8*)&qr[rb + (ks - 4) * 32 + lk * 8];
    }

    f32x4 oacc[8];
#pragma unroll
    for (int nf = 0; nf < 8; ++nf) oacc[nf] = {0.f, 0.f, 0.f, 0.f};
    float mrow[4] = {-1e30f, -1e30f, -1e30f, -1e30f};
    float lrow[4] = {0.f, 0.f, 0.f, 0.f};

    for (int k0 = 0; k0 <= q0; k0 += 64) {
        __syncthreads();                           // prior PV reads of Ks/Vs done
        // ---- stage K tile: 64 rows x 24 slots -----------------------------
#pragma unroll
        for (int i = 0; i < 6; ++i) {
            int c = tid + i * 256;                 // 0..1535
            int row = c / 24, sl = c - row * 24;
            int key = k0 + row;
            uint4 v;
            if (sl < 16) v = *(const uint4*)&kc[((size_t)(b * SEQ + key)) * kc_ld + h * DHEAD + sl * 8];
            else         v = *(const uint4*)&kr[((size_t)(b * SEQ + key)) * DROPE + (sl - 16) * 8];
            int sls = (sl & 24) | ((sl & 7) ^ (row & 7));
            *(uint4*)&Ks[(row * 24 + sls) * 8] = v;
        }
        // ---- stage V^T tile: 128 d-rows x 8 slots -------------------------
#pragma unroll
        for (int i = 0; i < 4; ++i) {
            int c = tid + i * 256;                 // 0..1023
            int d = c >> 3, sl = c & 7;
            uint4 v = *(const uint4*)&vt[((size_t)(bh * DHEAD + d)) * SEQ + k0 + sl * 8];
            *(uint4*)&Vs[(d * 8 + (sl ^ (d & 7))) * 8] = v;
        }
        __syncthreads();

        // ---- S = Q*K^T ----------------------------------------------------
        f32x4 sf[4];
#pragma unroll
        for (int nf = 0; nf < 4; ++nf) sf[nf] = {0.f, 0.f, 0.f, 0.f};
        __builtin_amdgcn_s_setprio(1);
#pragma unroll
        for (int ks = 0; ks < 6; ++ks) {
#pragma unroll
            for (int nf = 0; nf < 4; ++nf) {
                int row = nf * 16 + lr;
                int slb = ks * 4 + lk;             // 0..23
                int sls = (slb & 24) | ((slb & 7) ^ (row & 7));
                bf16x8 kf = *(const bf16x8*)&Ks[(row * 24 + sls) * 8];
                sf[nf] = __builtin_amdgcn_mfma_f32_16x16x32_bf16(qf[ks], kf, sf[nf], 0, 0, 0);
            }
        }
        __builtin_amdgcn_s_setprio(0);

        // scale + causal mask (diagonal tile only)
#pragma unroll
        for (int nf = 0; nf < 4; ++nf)
#pragma unroll
            for (int r = 0; r < 4; ++r) sf[nf][r] *= scale;
        if (k0 == q0) {
#pragma unroll
            for (int nf = 0; nf < 4; ++nf) {
                int key = k0 + nf * 16 + lr;
#pragma unroll
                for (int r = 0; r < 4; ++r) {
                    int q = q0 + wid * 16 + lk * 4 + r;
                    if (key > q) sf[nf][r] = -3.0e38f;
                }
            }
        }

        // ---- online softmax (per row r; stats across 16-lane group) -------
#pragma unroll
        for (int r = 0; r < 4; ++r) {
            float mx = fmaxf(fmaxf(sf[0][r], sf[1][r]), fmaxf(sf[2][r], sf[3][r]));
            mx = fmaxf(mx, __shfl_xor(mx, 1));
            mx = fmaxf(mx, __shfl_xor(mx, 2));
            mx = fmaxf(mx, __shfl_xor(mx, 4));
            mx = fmaxf(mx, __shfl_xor(mx, 8));
            const float mnew = fmaxf(mrow[r], mx);
            const float alpha = __expf(mrow[r] - mnew);
            float ps = 0.f;
#pragma unroll
            for (int nf = 0; nf < 4; ++nf) {
                float p = __expf(sf[nf][r] - mnew);
                sf[nf][r] = p;
                ps += p;
            }
            ps += __shfl_xor(ps, 1);
            ps += __shfl_xor(ps, 2);
            ps += __shfl_xor(ps, 4);
            ps += __shfl_xor(ps, 8);
            lrow[r] = lrow[r] * alpha + ps;
            mrow[r] = mnew;
#pragma unroll
            for (int nf = 0; nf < 8; ++nf) oacc[nf][r] *= alpha;
        }

        __syncthreads();                           // all waves' QK reads of Ks done

        // ---- P -> bf16 -> Ks-alias region (per-wave 2KB, swizzled) --------
        u16* pw = &Ks[wid * 1024];
#pragma unroll
        for (int nf = 0; nf < 4; ++nf)
#pragma unroll
            for (int r = 0; r < 4; ++r) {
                int prow = lk * 4 + r;
                int col = nf * 16 + lr;
                int sl = (col >> 3) ^ (prow & 7);
                pw[(prow * 8 + sl) * 8 + (col & 7)] = f2bf(sf[nf][r]);
            }

        // ---- out += P*V ---------------------------------------------------
        __builtin_amdgcn_s_setprio(1);
#pragma unroll
        for (int kp = 0; kp < 2; ++kp) {
            int sla = (kp * 4 + lk) ^ (lr & 7);
            bf16x8 pa = *(const bf16x8*)&pw[(lr * 8 + sla) * 8];
#pragma unroll
            for (int nf = 0; nf < 8; ++nf) {
                int vrow = nf * 16 + lr;
                int slv = (kp * 4 + lk) ^ (vrow & 7);
                bf16x8 vf = *(const bf16x8*)&Vs[(vrow * 8 + slv) * 8];
                oacc[nf] = __builtin_amdgcn_mfma_f32_16x16x32_bf16(pa, vf, oacc[nf], 0, 0, 0);
            }
        }
        __builtin_amdgcn_s_setprio(0);
    }

    // ---- epilogue (bf16) --------------------------------------------------
#pragma unroll
    for (int nf = 0; nf < 8; ++nf)
#pragma unroll
        for (int r = 0; r < 4; ++r) {
            int q = q0 + wid * 16 + lk * 4 + r;
            int d = nf * 16 + lr;
            ao[((size_t)(b * SEQ + q)) * (NHEAD * DHEAD) + h * DHEAD + d] =
                f2bf(oacc[nf][r] / lrow[r]);
        }
}

// ---------------------------------------------------------------------------
// Workspace map (u16 units; total 70,254,592 = 140.5 MB; 148.9 MB proven).
//   xb    [0,        8388608)   x bf16 [4096][2048]        (ao alias, later)
//   c1    [8388608, 15204352)   [4096][1664]: ckv|cq|krr|pad64
//   c2    [15204352,31981568)   [4096][4096]: kc|vv
//   c3    [31981568,44564480)   [4096][3072]: qc|qr_pre
//   qrb   [44564480,48758784)   [4096][1024]
//   krb   [48758784,49020928)   [4096][64]
//   vt    [49020928,57409536)   [2][2048][2048]
//   wcat1 [57409536,60817408)   [1664][2048] (rows 1600-1663 junk, harmless)
//   wcat2 [60817408,62914560)   [4096][512]
//   wcat3 [62914560,66060288)   [3072][1024]
//   woutT [66060288,70254592)   [2048][2048]
// Alias: ao = xb (xb dead after proj1; ao written by attn, read by final gemm).
// ---------------------------------------------------------------------------
extern "C" void kernel_launch(void* const* d_in, const int* in_sizes, int n_in,
                              void* d_out, int out_size, void* d_ws, size_t ws_size,
                              hipStream_t stream)
{
    const float* x     = (const float*)d_in[0];
    const float* w_dkv = (const float*)d_in[1];
    const float* w_uk  = (const float*)d_in[2];
    const float* w_uv  = (const float*)d_in[3];
    const float* w_dq  = (const float*)d_in[4];
    const float* w_uq  = (const float*)d_in[5];
    const float* w_qr  = (const float*)d_in[6];
    const float* w_kr  = (const float*)d_in[7];
    const float* w_out = (const float*)d_in[8];
    const float* delta = (const float*)d_in[9];
    float* out = (float*)d_out;
    u16* ws = (u16*)d_ws;

    const int M = BATCH * SEQ;   // 4096

    u16* xb    = ws;
    u16* ao    = ws;                         // alias (xb dead after proj1)
    u16* c1    = ws + 8388608;               // [4096][1664]
    u16* c2    = ws + 15204352;              // [4096][4096]
    u16* c3    = ws + 31981568;              // [4096][3072]
    u16* qrb   = ws + 44564480;              // [4096][1024]
    u16* krb   = ws + 48758784;              // [4096][64]
    u16* vt    = ws + 49020928;              // [2][2048][2048]
    u16* wcat1 = ws + 57409536;              // [1664][2048]
    u16* wcat2 = ws + 60817408;              // [4096][512]
    u16* wcat3 = ws + 62914560;              // [3072][1024]
    u16* woutT = ws + 66060288;              // [2048][2048]

    dim3 blk(256);

    // ---- converts / weight transposes (bf16) ------------------------------
    convert_bf16<<<dim3(8192), blk, 0, stream>>>(x, xb, M * DMODEL);
    transpose_f32_bf16<<<dim3(8, 32), blk, 0, stream>>>(w_dkv, wcat1, DMODEL, DCKV);                  // rows 0-511
    transpose_f32_bf16<<<dim3(16, 32), blk, 0, stream>>>(w_dq, wcat1 + 512 * 2048, DMODEL, DCQ);      // rows 512-1535
    transpose_f32_bf16<<<dim3(1, 32), blk, 0, stream>>>(w_kr, wcat1 + 1536 * 2048, DMODEL, DROPE);    // rows 1536-1599
    transpose_f32_bf16<<<dim3(32, 8), blk, 0, stream>>>(w_uk, wcat2, DCKV, 2048);                     // rows 0-2047
    transpose_f32_bf16<<<dim3(32, 8), blk, 0, stream>>>(w_uv, wcat2 + 2048 * 512, DCKV, 2048);        // rows 2048-4095
    transpose_f32_bf16<<<dim3(32, 16), blk, 0, stream>>>(w_uq, wcat3, DCQ, 2048);                     // rows 0-2047
    transpose_f32_bf16<<<dim3(16, 16), blk, 0, stream>>>(w_qr, wcat3 + 2048 * 1024, DCQ, 1024);       // rows 2048-3071
    transpose_f32_bf16<<<dim3(32, 32), blk, 0, stream>>>(w_out, woutT, 2048, DMODEL);

    // ---- merged projection GEMMs ------------------------------------------
    // proj1: x @ [w_dkv | w_dq | w_kr]  -> c1 [4096][1664]
    gemm_bf16<1><<<dim3(13, 32), blk, 0, stream>>>(xb, wcat1, c1, M, 1664, DMODEL, 2048, 2048, 1664);
    // proj2: ckv @ [w_uk | w_uv]        -> c2 [4096][4096]
    gemm_bf16<1><<<dim3(32, 32), blk, 0, stream>>>(c1, wcat2, c2, M, 4096, DCKV, 1664, 512, 4096);
    // proj3: cq @ [w_uq | w_qr]         -> c3 [4096][3072]
    gemm_bf16<1><<<dim3(24, 32), blk, 0, stream>>>(c1 + 512, wcat3, c3, M, 3072, DCQ, 1664, 1024, 3072);

    // ---- rope (bf16 in, bf16 out) -----------------------------------------
    pope_b16<<<dim3(8192), blk, 0, stream>>>(c3 + 2048, 3072, qrb, 1024, delta, NHEAD);
    pope_b16<<<dim3(512), blk, 0, stream>>>(c1 + 1536, 1664, krb, 64, delta, 1);

    // ---- V -> V^T per batch (vv = c2 cols 2048-4095) ----------------------
    transpose_b16<<<dim3(32, 32, BATCH), blk, 0, stream>>>(c2 + 2048, vt, SEQ, 2048, 4096,
                                                           (size_t)SEQ * 4096, (size_t)2048 * 2048);

    // ---- attention (bf16 out) ---------------------------------------------
    attn_mfma<<<dim3(SEQ / 64, BATCH * NHEAD), blk, 0, stream>>>(c3, 3072, qrb, c2, 4096, krb, vt, ao);

    // ---- output projection (fp32 out) -------------------------------------
    gemm_bf16<0><<<dim3(16, 32), blk, 0, stream>>>(ao, woutT, out, M, DMODEL, 2048, 2048, 2048, 2048);
}

// Round 8
// 818.016 us; speedup vs baseline: 1.0417x; 1.0417x over previous
//
#include <hip/hip_runtime.h>
#include <math.h>

#define BATCH  2
#define SEQ    2048
#define NHEAD  16
#define DMODEL 2048
#define DCKV   512
#define DCQ    1024
#define DHEAD  128
#define DROPE  64

typedef unsigned short u16;
typedef __attribute__((ext_vector_type(8))) short bf16x8;
typedef __attribute__((ext_vector_type(4))) float f32x4;

__device__ __forceinline__ u16 f2bf(float f) {           // RNE
    union { float f; unsigned u; } v; v.f = f;
    unsigned r = v.u + 0x7FFFu + ((v.u >> 16) & 1u);
    return (u16)(r >> 16);
}
__device__ __forceinline__ float bf2f(u16 h) {
    union { unsigned u; float f; } v; v.u = ((unsigned)h) << 16;
    return v.f;
}

// async global->LDS, 16B per lane; lds dest must be wave-uniform base (+lane*16)
__device__ __forceinline__ void gload_lds16(const u16* g, u16* l) {
    typedef const __attribute__((address_space(1))) u16* gp_t;
    typedef __attribute__((address_space(3))) u16* lp_t;
    __builtin_amdgcn_global_load_lds((gp_t)g, (lp_t)l, 16, 0, 0);
}

// ---------------------------------------------------------------------------
// flat f32 -> bf16 convert (n multiple of 4)
// ---------------------------------------------------------------------------
__global__ __launch_bounds__(256) void convert_bf16(const float* __restrict__ in,
                                                    u16* __restrict__ out, int n)
{
    int i = (blockIdx.x * 256 + threadIdx.x) * 4;
    if (i >= n) return;
    float4 v = *(const float4*)&in[i];
    union { u16 u[4]; uint2 w; } o;
    o.u[0] = f2bf(v.x); o.u[1] = f2bf(v.y); o.u[2] = f2bf(v.z); o.u[3] = f2bf(v.w);
    *(uint2*)&out[i] = o.w;
}

// ---------------------------------------------------------------------------
// transpose+convert: in f32 [R][C] -> out bf16 [C][R] (ldout = R).
// R,C multiples of 64.  grid (C/64, R/64).
// ---------------------------------------------------------------------------
__global__ __launch_bounds__(256) void transpose_f32_bf16(const float* __restrict__ in,
                                                          u16* __restrict__ out,
                                                          int R, int C)
{
    __shared__ u16 t[64][70];
    const int r0 = blockIdx.y * 64, c0 = blockIdx.x * 64;
    const int tid = threadIdx.x;
#pragma unroll
    for (int i = 0; i < 4; ++i) {
        int c = tid + i * 256;           // 0..1023
        int r = c >> 4, q = (c & 15) * 4;
        float4 v = *(const float4*)&in[(size_t)(r0 + r) * C + c0 + q];
        t[r][q + 0] = f2bf(v.x); t[r][q + 1] = f2bf(v.y);
        t[r][q + 2] = f2bf(v.z); t[r][q + 3] = f2bf(v.w);
    }
    __syncthreads();
#pragma unroll
    for (int i = 0; i < 2; ++i) {
        int c = tid + i * 256;           // 0..511
        int orow = c >> 3, os = (c & 7) * 8;
        union { u16 u[8]; uint4 w; } o;
#pragma unroll
        for (int j = 0; j < 8; ++j) o.u[j] = t[os + j][orow];
        *(uint4*)&out[(size_t)(c0 + orow) * R + r0 + os] = o.w;
    }
}

// ---------------------------------------------------------------------------
// transpose bf16 [R][C] (row stride ldin) -> bf16 [C][R] contig, batched z.
// ---------------------------------------------------------------------------
__global__ __launch_bounds__(256) void transpose_b16(const u16* __restrict__ in,
                                                     u16* __restrict__ out,
                                                     int R, int C, int ldin,
                                                     size_t sIn, size_t sOut)
{
    __shared__ u16 t[64][72];
    const u16* inz = in + (size_t)blockIdx.z * sIn;
    u16* outz = out + (size_t)blockIdx.z * sOut;
    const int r0 = blockIdx.y * 64, c0 = blockIdx.x * 64;
    const int tid = threadIdx.x;
#pragma unroll
    for (int i = 0; i < 2; ++i) {
        int c = tid + i * 256;           // 0..511
        int r = c >> 3, q = (c & 7) * 8;
        union { u16 u[8]; uint4 w; } v;
        v.w = *(const uint4*)&inz[(size_t)(r0 + r) * ldin + c0 + q];
#pragma unroll
        for (int j = 0; j < 8; ++j) t[r][q + j] = v.u[j];
    }
    __syncthreads();
#pragma unroll
    for (int i = 0; i < 2; ++i) {
        int c = tid + i * 256;
        int orow = c >> 3, os = (c & 7) * 8;
        union { u16 u[8]; uint4 w; } o;
#pragma unroll
        for (int j = 0; j < 8; ++j) o.u[j] = t[os + j][orow];
        *(uint4*)&outz[(size_t)(c0 + orow) * R + r0 + os] = o.w;
    }
}

// ---------------------------------------------------------------------------
// bf16 MFMA GEMM with strides: C[M,N] = A[M,K] * Bt[N,K]^T, fp32 accum.
// A row stride lda, Bt row stride ldb, C row stride ldc (elements).
// 128x128 tile, BK=64, 256 thr = 4 waves (2x2), wave = 64x64 = 4x4 frags.
// Staging: global_load_lds x16, pre-swizzled per-lane SOURCE + linear LDS
// dest; frag reads apply the same involutive XOR (16B slot ^= row&7).
// M mult 128, N mult 128 (Bt rows >= N), K mult 64.  lda/ldb 8-elem aligned.
// ---------------------------------------------------------------------------
template<int OUTBF16>
__global__ __launch_bounds__(256) void gemm_bf16(const u16* __restrict__ A,
                                                 const u16* __restrict__ Bt,
                                                 void* __restrict__ C,
                                                 int M, int N, int K,
                                                 int lda, int ldb, int ldc)
{
    __shared__ __align__(16) u16 As[128 * 64];
    __shared__ __align__(16) u16 Bs[128 * 64];

    const int tid = threadIdx.x;
    const int m0 = blockIdx.y * 128;
    const int n0 = blockIdx.x * 128;
    const int lane = tid & 63;
    const int wid = tid >> 6;
    const int wm = (wid & 1) * 64;
    const int wn = (wid >> 1) * 64;
    const int lr = lane & 15;
    const int lk = lane >> 4;

    f32x4 acc[4][4];
#pragma unroll
    for (int i = 0; i < 4; ++i)
#pragma unroll
        for (int j = 0; j < 4; ++j) acc[i][j] = {0.f, 0.f, 0.f, 0.f};

    for (int kt = 0; kt < K; kt += 64) {
        __syncthreads();
        // ---- stage A,B: linear LDS dest, inverse-swizzled global source ---
#pragma unroll
        for (int i = 0; i < 4; ++i) {
            int d0 = (i * 4 + wid) * 64;
            int d = d0 + lane;
            int row = d >> 3, sl = d & 7;
            gload_lds16(&A[(size_t)(m0 + row) * lda + kt + ((sl ^ (row & 7)) << 3)], &As[d0 * 8]);
        }
#pragma unroll
        for (int i = 0; i < 4; ++i) {
            int d0 = (i * 4 + wid) * 64;
            int d = d0 + lane;
            int row = d >> 3, sl = d & 7;
            gload_lds16(&Bt[(size_t)(n0 + row) * ldb + kt + ((sl ^ (row & 7)) << 3)], &Bs[d0 * 8]);
        }
        __syncthreads();   // drains vmcnt before s_barrier

#pragma unroll
        for (int ks = 0; ks < 2; ++ks) {
            bf16x8 af[4], bfr[4];
#pragma unroll
            for (int mf = 0; mf < 4; ++mf) {
                int row = wm + mf * 16 + lr;
                int sl = (ks * 4 + lk) ^ (row & 7);
                af[mf] = *(const bf16x8*)&As[row * 64 + sl * 8];
            }
#pragma unroll
            for (int nf = 0; nf < 4; ++nf) {
                int row = wn + nf * 16 + lr;
                int sl = (ks * 4 + lk) ^ (row & 7);
                bfr[nf] = *(const bf16x8*)&Bs[row * 64 + sl * 8];
            }
#pragma unroll
            for (int mf = 0; mf < 4; ++mf)
#pragma unroll
                for (int nf = 0; nf < 4; ++nf)
                    acc[mf][nf] = __builtin_amdgcn_mfma_f32_16x16x32_bf16(
                        af[mf], bfr[nf], acc[mf][nf], 0, 0, 0);
        }
    }

    const int crow0 = m0 + wm + lk * 4;
    const int ccol0 = n0 + wn + lr;
#pragma unroll
    for (int mf = 0; mf < 4; ++mf)
#pragma unroll
        for (int nf = 0; nf < 4; ++nf) {
            int coln = ccol0 + nf * 16;
            if (coln < N) {
#pragma unroll
                for (int r = 0; r < 4; ++r) {
                    int rm = crow0 + mf * 16 + r;
                    float v = acc[mf][nf][r];
                    if (OUTBF16) ((u16*)C)[(size_t)rm * ldc + coln] = f2bf(v);
                    else         ((float*)C)[(size_t)rm * ldc + coln] = v;
                }
            }
        }
}

// ---------------------------------------------------------------------------
// pope: read bf16 [B*S rows, stride ldin] (hcols*64 wide), softplus+rotate,
// write bf16 [B*S rows, stride ldout].  pair (j, j+32) shares angle j.
// ---------------------------------------------------------------------------
__device__ __forceinline__ float softplusf(float v)
{
    if (v > 20.f) return v;
    return log1pf(__expf(v));
}

__global__ __launch_bounds__(256) void pope_b16(const u16* __restrict__ in, int ldin,
                                                u16* __restrict__ outb, int ldout,
                                                const float* __restrict__ delta,
                                                int hcols)
{
    const int idx = blockIdx.x * 256 + threadIdx.x;
    const int total = BATCH * SEQ * hcols * 32;
    if (idx >= total) return;
    const int j = idx & 31;
    const int h = (idx >> 5) % hcols;
    const int rowid = idx / (32 * hcols);
    const int s = rowid % SEQ;

    const float theta = __expf(-(2.0f * (float)j) * (9.210340371976184f / 64.0f));
    const float ang = (float)s * theta + delta[j];
    float sn, cs;
    sincosf(ang, &sn, &cs);

    const u16* row = in + (size_t)rowid * ldin + h * 64;
    u16* orow = outb + (size_t)rowid * ldout + h * 64;
    const float mu1 = softplusf(bf2f(row[j]));
    const float mu2 = softplusf(bf2f(row[j + 32]));
    orow[j]      = f2bf(mu1 * cs - mu2 * sn);
    orow[j + 32] = f2bf(mu1 * sn + mu2 * cs);
}

// ---------------------------------------------------------------------------
// MFMA flash attention (64-row q-tile, round-3 structure + P-alias, natural
// VGPR).  grid (SEQ/64, BATCH*NHEAD), 256 thr = 4 waves; wave w owns q-rows
// [w*16, w*16+16).  LDS: Ks 24KB (P aliased per-wave after 3rd barrier) +
// Vs 16KB = 40KB -> 4 blocks/CU; VGPR ~128 -> 16 waves/CU (no forced cap:
// r7's (256,4) forced 64 VGPR -> 449MB spill traffic, 2.6x regression).
// ---------------------------------------------------------------------------
__global__ __launch_bounds__(256) void attn_mfma(const u16* __restrict__ qc, int qc_ld,
                                                 const u16* __restrict__ qr,
                                                 const u16* __restrict__ kc, int kc_ld,
                                                 const u16* __restrict__ kr,
                                                 const u16* __restrict__ vt,
                                                 u16* __restrict__ ao)
{
    __shared__ __align__(16) u16 Ks[64 * 192];     // [key][24 slots]; P alias
    __shared__ __align__(16) u16 Vs[128 * 64];     // [d][8 slots]

    const int qi = gridDim.x - 1 - blockIdx.x;     // big blocks first
    const int q0 = qi * 64;
    const int bh = blockIdx.y;
    const int b = bh >> 4, h = bh & 15;
    const int tid = threadIdx.x, lane = tid & 63, wid = tid >> 6;
    const int lr = lane & 15, lk = lane >> 4;
    const float scale = 0.07216878364870323f;      // 1/sqrt(192)

    // Q fragments (A-operand rows = lane&15), hoisted
    bf16x8 qf[6];
    {
        const int sq = q0 + wid * 16 + lr;
        const size_t qb = ((size_t)(b * SEQ + sq)) * qc_ld + h * DHEAD;
        const size_t rb = ((size_t)(b * SEQ + sq)) * (NHEAD * DROPE) + h * DROPE;
#pragma unroll
        for (int ks = 0; ks < 4; ++ks) qf[ks] = *(const bf16x8*)&qc[qb + ks * 32 + lk * 8];
#pragma unroll
        for (int ks = 4; ks < 6; ++ks) qf[ks] = *(const bf16x8*)&qr[rb + (ks - 4) * 32 + lk * 8];
    }

    f32x4 oacc[8];
#pragma unroll
    for (int nf = 0; nf < 8; ++nf) oacc[nf] = {0.f, 0.f, 0.f, 0.f};
    float mrow[4] = {-1e30f, -1e30f, -1e30f, -1e30f};
    float lrow[4] = {0.f, 0.f, 0.f, 0.f};

    for (int k0 = 0; k0 <= q0; k0 += 64) {
        __syncthreads();                           // prior PV reads of Ks/Vs done
        // ---- stage K tile: 64 rows x 24 slots -----------------------------
#pragma unroll
        for (int i = 0; i < 6; ++i) {
            int c = tid + i * 256;                 // 0..1535
            int row = c / 24, sl = c - row * 24;
            int key = k0 + row;
            uint4 v;
            if (sl < 16) v = *(const uint4*)&kc[((size_t)(b * SEQ + key)) * kc_ld + h * DHEAD + sl * 8];
            else         v = *(const uint4*)&kr[((size_t)(b * SEQ + key)) * DROPE + (sl - 16) * 8];
            int sls = (sl & 24) | ((sl & 7) ^ (row & 7));
            *(uint4*)&Ks[(row * 24 + sls) * 8] = v;
        }
        // ---- stage V^T tile: 128 d-rows x 8 slots -------------------------
#pragma unroll
        for (int i = 0; i < 4; ++i) {
            int c = tid + i * 256;                 // 0..1023
            int d = c >> 3, sl = c & 7;
            uint4 v = *(const uint4*)&vt[((size_t)(bh * DHEAD + d)) * SEQ + k0 + sl * 8];
            *(uint4*)&Vs[(d * 8 + (sl ^ (d & 7))) * 8] = v;
        }
        __syncthreads();

        // ---- S = Q*K^T ----------------------------------------------------
        f32x4 sf[4];
#pragma unroll
        for (int nf = 0; nf < 4; ++nf) sf[nf] = {0.f, 0.f, 0.f, 0.f};
        __builtin_amdgcn_s_setprio(1);
#pragma unroll
        for (int ks = 0; ks < 6; ++ks) {
#pragma unroll
            for (int nf = 0; nf < 4; ++nf) {
                int row = nf * 16 + lr;
                int slb = ks * 4 + lk;             // 0..23
                int sls = (slb & 24) | ((slb & 7) ^ (row & 7));
                bf16x8 kf = *(const bf16x8*)&Ks[(row * 24 + sls) * 8];
                sf[nf] = __builtin_amdgcn_mfma_f32_16x16x32_bf16(qf[ks], kf, sf[nf], 0, 0, 0);
            }
        }
        __builtin_amdgcn_s_setprio(0);

        // scale + causal mask (diagonal tile only)
#pragma unroll
        for (int nf = 0; nf < 4; ++nf)
#pragma unroll
            for (int r = 0; r < 4; ++r) sf[nf][r] *= scale;
        if (k0 == q0) {
#pragma unroll
            for (int nf = 0; nf < 4; ++nf) {
                int key = k0 + nf * 16 + lr;
#pragma unroll
                for (int r = 0; r < 4; ++r) {
                    int q = q0 + wid * 16 + lk * 4 + r;
                    if (key > q) sf[nf][r] = -3.0e38f;
                }
            }
        }

        // ---- online softmax (per row r; stats across 16-lane group) -------
#pragma unroll
        for (int r = 0; r < 4; ++r) {
            float mx = fmaxf(fmaxf(sf[0][r], sf[1][r]), fmaxf(sf[2][r], sf[3][r]));
            mx = fmaxf(mx, __shfl_xor(mx, 1));
            mx = fmaxf(mx, __shfl_xor(mx, 2));
            mx = fmaxf(mx, __shfl_xor(mx, 4));
            mx = fmaxf(mx, __shfl_xor(mx, 8));
            const float mnew = fmaxf(mrow[r], mx);
            const float alpha = __expf(mrow[r] - mnew);
            float ps = 0.f;
#pragma unroll
            for (int nf = 0; nf < 4; ++nf) {
                float p = __expf(sf[nf][r] - mnew);
                sf[nf][r] = p;
                ps += p;
            }
            ps += __shfl_xor(ps, 1);
            ps += __shfl_xor(ps, 2);
            ps += __shfl_xor(ps, 4);
            ps += __shfl_xor(ps, 8);
            lrow[r] = lrow[r] * alpha + ps;
            mrow[r] = mnew;
#pragma unroll
            for (int nf = 0; nf < 8; ++nf) oacc[nf][r] *= alpha;
        }

        __syncthreads();                           // all waves' QK reads of Ks done

        // ---- P -> bf16 -> Ks-alias region (per-wave 2KB, swizzled) --------
        u16* pw = &Ks[wid * 1024];
#pragma unroll
        for (int nf = 0; nf < 4; ++nf)
#pragma unroll
            for (int r = 0; r < 4; ++r) {
                int prow = lk * 4 + r;
                int col = nf * 16 + lr;
                int sl = (col >> 3) ^ (prow & 7);
                pw[(prow * 8 + sl) * 8 + (col & 7)] = f2bf(sf[nf][r]);
            }

        // ---- out += P*V ---------------------------------------------------
        __builtin_amdgcn_s_setprio(1);
#pragma unroll
        for (int kp = 0; kp < 2; ++kp) {
            int sla = (kp * 4 + lk) ^ (lr & 7);
            bf16x8 pa = *(const bf16x8*)&pw[(lr * 8 + sla) * 8];
#pragma unroll
            for (int nf = 0; nf < 8; ++nf) {
                int vrow = nf * 16 + lr;
                int slv = (kp * 4 + lk) ^ (vrow & 7);
                bf16x8 vf = *(const bf16x8*)&Vs[(vrow * 8 + slv) * 8];
                oacc[nf] = __builtin_amdgcn_mfma_f32_16x16x32_bf16(pa, vf, oacc[nf], 0, 0, 0);
            }
        }
        __builtin_amdgcn_s_setprio(0);
    }

    // ---- epilogue (bf16) --------------------------------------------------
#pragma unroll
    for (int nf = 0; nf < 8; ++nf)
#pragma unroll
        for (int r = 0; r < 4; ++r) {
            int q = q0 + wid * 16 + lk * 4 + r;
            int d = nf * 16 + lr;
            ao[((size_t)(b * SEQ + q)) * (NHEAD * DHEAD) + h * DHEAD + d] =
                f2bf(oacc[nf][r] / lrow[r]);
        }
}

// ---------------------------------------------------------------------------
// Workspace map (u16 units; total 70,254,592 = 140.5 MB; 148.9 MB proven).
//   xb    [0,        8388608)   x bf16 [4096][2048]        (ao alias, later)
//   c1    [8388608, 15204352)   [4096][1664]: ckv|cq|krr|pad64
//   c2    [15204352,31981568)   [4096][4096]: kc|vv
//   c3    [31981568,44564480)   [4096][3072]: qc|qr_pre
//   qrb   [44564480,48758784)   [4096][1024]
//   krb   [48758784,49020928)   [4096][64]
//   vt    [49020928,57409536)   [2][2048][2048]
//   wcat1 [57409536,60817408)   [1664][2048] (rows 1600-1663 junk, harmless)
//   wcat2 [60817408,62914560)   [4096][512]
//   wcat3 [62914560,66060288)   [3072][1024]
//   woutT [66060288,70254592)   [2048][2048]
// Alias: ao = xb (xb dead after proj1; ao written by attn, read by final gemm).
// ---------------------------------------------------------------------------
extern "C" void kernel_launch(void* const* d_in, const int* in_sizes, int n_in,
                              void* d_out, int out_size, void* d_ws, size_t ws_size,
                              hipStream_t stream)
{
    const float* x     = (const float*)d_in[0];
    const float* w_dkv = (const float*)d_in[1];
    const float* w_uk  = (const float*)d_in[2];
    const float* w_uv  = (const float*)d_in[3];
    const float* w_dq  = (const float*)d_in[4];
    const float* w_uq  = (const float*)d_in[5];
    const float* w_qr  = (const float*)d_in[6];
    const float* w_kr  = (const float*)d_in[7];
    const float* w_out = (const float*)d_in[8];
    const float* delta = (const float*)d_in[9];
    float* out = (float*)d_out;
    u16* ws = (u16*)d_ws;

    const int M = BATCH * SEQ;   // 4096

    u16* xb    = ws;
    u16* ao    = ws;                         // alias (xb dead after proj1)
    u16* c1    = ws + 8388608;               // [4096][1664]
    u16* c2    = ws + 15204352;              // [4096][4096]
    u16* c3    = ws + 31981568;              // [4096][3072]
    u16* qrb   = ws + 44564480;              // [4096][1024]
    u16* krb   = ws + 48758784;              // [4096][64]
    u16* vt    = ws + 49020928;              // [2][2048][2048]
    u16* wcat1 = ws + 57409536;              // [1664][2048]
    u16* wcat2 = ws + 60817408;              // [4096][512]
    u16* wcat3 = ws + 62914560;              // [3072][1024]
    u16* woutT = ws + 66060288;              // [2048][2048]

    dim3 blk(256);

    // ---- converts / weight transposes (bf16) ------------------------------
    convert_bf16<<<dim3(8192), blk, 0, stream>>>(x, xb, M * DMODEL);
    transpose_f32_bf16<<<dim3(8, 32), blk, 0, stream>>>(w_dkv, wcat1, DMODEL, DCKV);                  // rows 0-511
    transpose_f32_bf16<<<dim3(16, 32), blk, 0, stream>>>(w_dq, wcat1 + 512 * 2048, DMODEL, DCQ);      // rows 512-1535
    transpose_f32_bf16<<<dim3(1, 32), blk, 0, stream>>>(w_kr, wcat1 + 1536 * 2048, DMODEL, DROPE);    // rows 1536-1599
    transpose_f32_bf16<<<dim3(32, 8), blk, 0, stream>>>(w_uk, wcat2, DCKV, 2048);                     // rows 0-2047
    transpose_f32_bf16<<<dim3(32, 8), blk, 0, stream>>>(w_uv, wcat2 + 2048 * 512, DCKV, 2048);        // rows 2048-4095
    transpose_f32_bf16<<<dim3(32, 16), blk, 0, stream>>>(w_uq, wcat3, DCQ, 2048);                     // rows 0-2047
    transpose_f32_bf16<<<dim3(16, 16), blk, 0, stream>>>(w_qr, wcat3 + 2048 * 1024, DCQ, 1024);       // rows 2048-3071
    transpose_f32_bf16<<<dim3(32, 32), blk, 0, stream>>>(w_out, woutT, 2048, DMODEL);

    // ---- merged projection GEMMs ------------------------------------------
    // proj1: x @ [w_dkv | w_dq | w_kr]  -> c1 [4096][1664]
    gemm_bf16<1><<<dim3(13, 32), blk, 0, stream>>>(xb, wcat1, c1, M, 1664, DMODEL, 2048, 2048, 1664);
    // proj2: ckv @ [w_uk | w_uv]        -> c2 [4096][4096]
    gemm_bf16<1><<<dim3(32, 32), blk, 0, stream>>>(c1, wcat2, c2, M, 4096, DCKV, 1664, 512, 4096);
    // proj3: cq @ [w_uq | w_qr]         -> c3 [4096][3072]
    gemm_bf16<1><<<dim3(24, 32), blk, 0, stream>>>(c1 + 512, wcat3, c3, M, 3072, DCQ, 1664, 1024, 3072);

    // ---- rope (bf16 in, bf16 out) -----------------------------------------
    pope_b16<<<dim3(8192), blk, 0, stream>>>(c3 + 2048, 3072, qrb, 1024, delta, NHEAD);
    pope_b16<<<dim3(512), blk, 0, stream>>>(c1 + 1536, 1664, krb, 64, delta, 1);

    // ---- V -> V^T per batch (vv = c2 cols 2048-4095) ----------------------
    transpose_b16<<<dim3(32, 32, BATCH), blk, 0, stream>>>(c2 + 2048, vt, SEQ, 2048, 4096,
                                                           (size_t)SEQ * 4096, (size_t)2048 * 2048);

    // ---- attention (bf16 out) ---------------------------------------------
    attn_mfma<<<dim3(SEQ / 64, BATCH * NHEAD), blk, 0, stream>>>(c3, 3072, qrb, c2, 4096, krb, vt, ao);

    // ---- output projection (fp32 out) -------------------------------------
    gemm_bf16<0><<<dim3(16, 32), blk, 0, stream>>>(ao, woutT, out, M, DMODEL, 2048, 2048, 2048, 2048);
}

// Round 11
// 644.650 us; speedup vs baseline: 1.3218x; 1.2689x over previous
//
#include <hip/hip_runtime.h>
#include <math.h>

#define BATCH  2
#define SEQ    2048
#define NHEAD  16
#define DMODEL 2048
#define DCKV   512
#define DCQ    1024
#define DHEAD  128
#define DROPE  64

// attention input row strides (compile-time: runtime strides cost VGPRs ->
// r8's 132 VGPR crossed the 128 occupancy cliff, halving waves/CU)
#define QCLD 3072
#define KCLD 4096

typedef unsigned short u16;
typedef __attribute__((ext_vector_type(8))) short bf16x8;
typedef __attribute__((ext_vector_type(4))) float f32x4;

__device__ __forceinline__ u16 f2bf(float f) {           // RNE
    union { float f; unsigned u; } v; v.f = f;
    unsigned r = v.u + 0x7FFFu + ((v.u >> 16) & 1u);
    return (u16)(r >> 16);
}
__device__ __forceinline__ float bf2f(u16 h) {
    union { unsigned u; float f; } v; v.u = ((unsigned)h) << 16;
    return v.f;
}

// async global->LDS, 16B per lane; lds dest must be wave-uniform base (+lane*16)
__device__ __forceinline__ void gload_lds16(const u16* g, u16* l) {
    typedef const __attribute__((address_space(1))) u16* gp_t;
    typedef __attribute__((address_space(3))) u16* lp_t;
    __builtin_amdgcn_global_load_lds((gp_t)g, (lp_t)l, 16, 0, 0);
}

// ---------------------------------------------------------------------------
// flat f32 -> bf16 convert (n multiple of 4)
// ---------------------------------------------------------------------------
__global__ __launch_bounds__(256) void convert_bf16(const float* __restrict__ in,
                                                    u16* __restrict__ out, int n)
{
    int i = (blockIdx.x * 256 + threadIdx.x) * 4;
    if (i >= n) return;
    float4 v = *(const float4*)&in[i];
    union { u16 u[4]; uint2 w; } o;
    o.u[0] = f2bf(v.x); o.u[1] = f2bf(v.y); o.u[2] = f2bf(v.z); o.u[3] = f2bf(v.w);
    *(uint2*)&out[i] = o.w;
}

// ---------------------------------------------------------------------------
// transpose+convert: in f32 [R][C] -> out bf16 [C][R] (ldout = R).
// R,C multiples of 64.  grid (C/64, R/64).
// ---------------------------------------------------------------------------
__global__ __launch_bounds__(256) void transpose_f32_bf16(const float* __restrict__ in,
                                                          u16* __restrict__ out,
                                                          int R, int C)
{
    __shared__ u16 t[64][70];
    const int r0 = blockIdx.y * 64, c0 = blockIdx.x * 64;
    const int tid = threadIdx.x;
#pragma unroll
    for (int i = 0; i < 4; ++i) {
        int c = tid + i * 256;           // 0..1023
        int r = c >> 4, q = (c & 15) * 4;
        float4 v = *(const float4*)&in[(size_t)(r0 + r) * C + c0 + q];
        t[r][q + 0] = f2bf(v.x); t[r][q + 1] = f2bf(v.y);
        t[r][q + 2] = f2bf(v.z); t[r][q + 3] = f2bf(v.w);
    }
    __syncthreads();
#pragma unroll
    for (int i = 0; i < 2; ++i) {
        int c = tid + i * 256;           // 0..511
        int orow = c >> 3, os = (c & 7) * 8;
        union { u16 u[8]; uint4 w; } o;
#pragma unroll
        for (int j = 0; j < 8; ++j) o.u[j] = t[os + j][orow];
        *(uint4*)&out[(size_t)(c0 + orow) * R + r0 + os] = o.w;
    }
}

// ---------------------------------------------------------------------------
// transpose bf16 [R][C] (row stride ldin) -> bf16 [C][R] contig, batched z.
// ---------------------------------------------------------------------------
__global__ __launch_bounds__(256) void transpose_b16(const u16* __restrict__ in,
                                                     u16* __restrict__ out,
                                                     int R, int C, int ldin,
                                                     size_t sIn, size_t sOut)
{
    __shared__ u16 t[64][72];
    const u16* inz = in + (size_t)blockIdx.z * sIn;
    u16* outz = out + (size_t)blockIdx.z * sOut;
    const int r0 = blockIdx.y * 64, c0 = blockIdx.x * 64;
    const int tid = threadIdx.x;
#pragma unroll
    for (int i = 0; i < 2; ++i) {
        int c = tid + i * 256;           // 0..511
        int r = c >> 3, q = (c & 7) * 8;
        union { u16 u[8]; uint4 w; } v;
        v.w = *(const uint4*)&inz[(size_t)(r0 + r) * ldin + c0 + q];
#pragma unroll
        for (int j = 0; j < 8; ++j) t[r][q + j] = v.u[j];
    }
    __syncthreads();
#pragma unroll
    for (int i = 0; i < 2; ++i) {
        int c = tid + i * 256;
        int orow = c >> 3, os = (c & 7) * 8;
        union { u16 u[8]; uint4 w; } o;
#pragma unroll
        for (int j = 0; j < 8; ++j) o.u[j] = t[os + j][orow];
        *(uint4*)&outz[(size_t)(c0 + orow) * R + r0 + os] = o.w;
    }
}

// ---------------------------------------------------------------------------
// bf16 MFMA GEMM with strides: C[M,N] = A[M,K] * Bt[N,K]^T, fp32 accum.
// 128x128 tile, BK=64, 256 thr = 4 waves (2x2), wave = 64x64 = 4x4 frags.
// Staging: global_load_lds x16, pre-swizzled per-lane SOURCE + linear LDS
// dest; frag reads apply the same involutive XOR (16B slot ^= row&7).
// M mult 128, N mult 128 (Bt rows >= N), K mult 64.  lda/ldb 8-elem aligned.
// ---------------------------------------------------------------------------
template<int OUTBF16>
__global__ __launch_bounds__(256) void gemm_bf16(const u16* __restrict__ A,
                                                 const u16* __restrict__ Bt,
                                                 void* __restrict__ C,
                                                 int M, int N, int K,
                                                 int lda, int ldb, int ldc)
{
    __shared__ __align__(16) u16 As[128 * 64];
    __shared__ __align__(16) u16 Bs[128 * 64];

    const int tid = threadIdx.x;
    const int m0 = blockIdx.y * 128;
    const int n0 = blockIdx.x * 128;
    const int lane = tid & 63;
    const int wid = tid >> 6;
    const int wm = (wid & 1) * 64;
    const int wn = (wid >> 1) * 64;
    const int lr = lane & 15;
    const int lk = lane >> 4;

    f32x4 acc[4][4];
#pragma unroll
    for (int i = 0; i < 4; ++i)
#pragma unroll
        for (int j = 0; j < 4; ++j) acc[i][j] = {0.f, 0.f, 0.f, 0.f};

    for (int kt = 0; kt < K; kt += 64) {
        __syncthreads();
        // ---- stage A,B: linear LDS dest, inverse-swizzled global source ---
#pragma unroll
        for (int i = 0; i < 4; ++i) {
            int d0 = (i * 4 + wid) * 64;
            int d = d0 + lane;
            int row = d >> 3, sl = d & 7;
            gload_lds16(&A[(size_t)(m0 + row) * lda + kt + ((sl ^ (row & 7)) << 3)], &As[d0 * 8]);
        }
#pragma unroll
        for (int i = 0; i < 4; ++i) {
            int d0 = (i * 4 + wid) * 64;
            int d = d0 + lane;
            int row = d >> 3, sl = d & 7;
            gload_lds16(&Bt[(size_t)(n0 + row) * ldb + kt + ((sl ^ (row & 7)) << 3)], &Bs[d0 * 8]);
        }
        __syncthreads();   // drains vmcnt before s_barrier

#pragma unroll
        for (int ks = 0; ks < 2; ++ks) {
            bf16x8 af[4], bfr[4];
#pragma unroll
            for (int mf = 0; mf < 4; ++mf) {
                int row = wm + mf * 16 + lr;
                int sl = (ks * 4 + lk) ^ (row & 7);
                af[mf] = *(const bf16x8*)&As[row * 64 + sl * 8];
            }
#pragma unroll
            for (int nf = 0; nf < 4; ++nf) {
                int row = wn + nf * 16 + lr;
                int sl = (ks * 4 + lk) ^ (row & 7);
                bfr[nf] = *(const bf16x8*)&Bs[row * 64 + sl * 8];
            }
#pragma unroll
            for (int mf = 0; mf < 4; ++mf)
#pragma unroll
                for (int nf = 0; nf < 4; ++nf)
                    acc[mf][nf] = __builtin_amdgcn_mfma_f32_16x16x32_bf16(
                        af[mf], bfr[nf], acc[mf][nf], 0, 0, 0);
        }
    }

    const int crow0 = m0 + wm + lk * 4;
    const int ccol0 = n0 + wn + lr;
#pragma unroll
    for (int mf = 0; mf < 4; ++mf)
#pragma unroll
        for (int nf = 0; nf < 4; ++nf) {
            int coln = ccol0 + nf * 16;
            if (coln < N) {
#pragma unroll
                for (int r = 0; r < 4; ++r) {
                    int rm = crow0 + mf * 16 + r;
                    float v = acc[mf][nf][r];
                    if (OUTBF16) ((u16*)C)[(size_t)rm * ldc + coln] = f2bf(v);
                    else         ((float*)C)[(size_t)rm * ldc + coln] = v;
                }
            }
        }
}

// ---------------------------------------------------------------------------
// pope: read bf16 [B*S rows, stride ldin] (hcols*64 wide), softplus+rotate,
// write bf16 [B*S rows, stride ldout].  pair (j, j+32) shares angle j.
// ---------------------------------------------------------------------------
__device__ __forceinline__ float softplusf(float v)
{
    if (v > 20.f) return v;
    return log1pf(__expf(v));
}

__global__ __launch_bounds__(256) void pope_b16(const u16* __restrict__ in, int ldin,
                                                u16* __restrict__ outb, int ldout,
                                                const float* __restrict__ delta,
                                                int hcols)
{
    const int idx = blockIdx.x * 256 + threadIdx.x;
    const int total = BATCH * SEQ * hcols * 32;
    if (idx >= total) return;
    const int j = idx & 31;
    const int h = (idx >> 5) % hcols;
    const int rowid = idx / (32 * hcols);
    const int s = rowid % SEQ;

    const float theta = __expf(-(2.0f * (float)j) * (9.210340371976184f / 64.0f));
    const float ang = (float)s * theta + delta[j];
    float sn, cs;
    sincosf(ang, &sn, &cs);

    const u16* row = in + (size_t)rowid * ldin + h * 64;
    u16* orow = outb + (size_t)rowid * ldout + h * 64;
    const float mu1 = softplusf(bf2f(row[j]));
    const float mu2 = softplusf(bf2f(row[j + 32]));
    orow[j]      = f2bf(mu1 * cs - mu2 * sn);
    orow[j + 32] = f2bf(mu1 * sn + mu2 * cs);
}

// ---------------------------------------------------------------------------
// MFMA flash attention — round-3 proven structure restored:
// 64-row q-tile, 4 waves (wave w owns q-rows [w*16,w*16+16)), dedicated Ps
// buffer, TWO barriers per k-tile (waves slip phases -> MFMA/VALU overlap
// across waves; r7/r8's 3rd barrier locksteps pipes and cost 2.4x).
// LDS: Ks 24KB + Vs 16KB + Ps 8KB = 48KB -> 3 blocks/CU; strides are
// compile-time (QCLD/KCLD) to keep VGPR <= 128 (16 waves/CU allowed).
// ---------------------------------------------------------------------------
__global__ __launch_bounds__(256) void attn_mfma(const u16* __restrict__ qc,
                                                 const u16* __restrict__ qr,
                                                 const u16* __restrict__ kc,
                                                 const u16* __restrict__ kr,
                                                 const u16* __restrict__ vt,
                                                 u16* __restrict__ ao)
{
    __shared__ __align__(16) u16 Ks[64 * 192];     // [key][24 slots]
    __shared__ __align__(16) u16 Vs[128 * 64];     // [d][8 slots]
    __shared__ __align__(16) u16 Ps[4][16 * 64];   // per-wave [q][8 slots]

    const int qi = gridDim.x - 1 - blockIdx.x;     // big blocks first
    const int q0 = qi * 64;
    const int bh = blockIdx.y;
    const int b = bh >> 4, h = bh & 15;
    const int tid = threadIdx.x, lane = tid & 63, wid = tid >> 6;
    const int lr = lane & 15, lk = lane >> 4;
    const float scale = 0.07216878364870323f;      // 1/sqrt(192)

    // Q fragments (A-operand rows = lane&15), hoisted
    bf16x8 qf[6];
    {
        const int sq = q0 + wid * 16 + lr;
        const size_t qb = ((size_t)(b * SEQ + sq)) * QCLD + h * DHEAD;
        const size_t rb = ((size_t)(b * SEQ + sq)) * (NHEAD * DROPE) + h * DROPE;
#pragma unroll
        for (int ks = 0; ks < 4; ++ks) qf[ks] = *(const bf16x8*)&qc[qb + ks * 32 + lk * 8];
#pragma unroll
        for (int ks = 4; ks < 6; ++ks) qf[ks] = *(const bf16x8*)&qr[rb + (ks - 4) * 32 + lk * 8];
    }

    f32x4 oacc[8];
#pragma unroll
    for (int nf = 0; nf < 8; ++nf) oacc[nf] = {0.f, 0.f, 0.f, 0.f};
    float mrow[4] = {-1e30f, -1e30f, -1e30f, -1e30f};
    float lrow[4] = {0.f, 0.f, 0.f, 0.f};

    for (int k0 = 0; k0 <= q0; k0 += 64) {
        __syncthreads();                           // prior tile's PV/P reads done
        // ---- stage K tile: 64 rows x 24 slots -----------------------------
#pragma unroll
        for (int i = 0; i < 6; ++i) {
            int c = tid + i * 256;                 // 0..1535
            int row = c / 24, sl = c - row * 24;
            int key = k0 + row;
            uint4 v;
            if (sl < 16) v = *(const uint4*)&kc[((size_t)(b * SEQ + key)) * KCLD + h * DHEAD + sl * 8];
            else         v = *(const uint4*)&kr[((size_t)(b * SEQ + key)) * DROPE + (sl - 16) * 8];
            int sls = (sl & 24) | ((sl & 7) ^ (row & 7));
            *(uint4*)&Ks[(row * 24 + sls) * 8] = v;
        }
        // ---- stage V^T tile: 128 d-rows x 8 slots -------------------------
#pragma unroll
        for (int i = 0; i < 4; ++i) {
            int c = tid + i * 256;                 // 0..1023
            int d = c >> 3, sl = c & 7;
            uint4 v = *(const uint4*)&vt[((size_t)(bh * DHEAD + d)) * SEQ + k0 + sl * 8];
            *(uint4*)&Vs[(d * 8 + (sl ^ (d & 7))) * 8] = v;
        }
        __syncthreads();

        // ---- S = Q*K^T ----------------------------------------------------
        f32x4 sf[4];
#pragma unroll
        for (int nf = 0; nf < 4; ++nf) sf[nf] = {0.f, 0.f, 0.f, 0.f};
        __builtin_amdgcn_s_setprio(1);
#pragma unroll
        for (int ks = 0; ks < 6; ++ks) {
#pragma unroll
            for (int nf = 0; nf < 4; ++nf) {
                int row = nf * 16 + lr;
                int slb = ks * 4 + lk;             // 0..23
                int sls = (slb & 24) | ((slb & 7) ^ (row & 7));
                bf16x8 kf = *(const bf16x8*)&Ks[(row * 24 + sls) * 8];
                sf[nf] = __builtin_amdgcn_mfma_f32_16x16x32_bf16(qf[ks], kf, sf[nf], 0, 0, 0);
            }
        }
        __builtin_amdgcn_s_setprio(0);

        // scale + causal mask (diagonal tile only)
#pragma unroll
        for (int nf = 0; nf < 4; ++nf)
#pragma unroll
            for (int r = 0; r < 4; ++r) sf[nf][r] *= scale;
        if (k0 == q0) {
#pragma unroll
            for (int nf = 0; nf < 4; ++nf) {
                int key = k0 + nf * 16 + lr;
#pragma unroll
                for (int r = 0; r < 4; ++r) {
                    int q = q0 + wid * 16 + lk * 4 + r;
                    if (key > q) sf[nf][r] = -3.0e38f;
                }
            }
        }

        // ---- online softmax (per row r; stats across 16-lane group) -------
#pragma unroll
        for (int r = 0; r < 4; ++r) {
            float mx = fmaxf(fmaxf(sf[0][r], sf[1][r]), fmaxf(sf[2][r], sf[3][r]));
            mx = fmaxf(mx, __shfl_xor(mx, 1));
            mx = fmaxf(mx, __shfl_xor(mx, 2));
            mx = fmaxf(mx, __shfl_xor(mx, 4));
            mx = fmaxf(mx, __shfl_xor(mx, 8));
            const float mnew = fmaxf(mrow[r], mx);
            const float alpha = __expf(mrow[r] - mnew);
            float ps = 0.f;
#pragma unroll
            for (int nf = 0; nf < 4; ++nf) {
                float p = __expf(sf[nf][r] - mnew);
                sf[nf][r] = p;
                ps += p;
            }
            ps += __shfl_xor(ps, 1);
            ps += __shfl_xor(ps, 2);
            ps += __shfl_xor(ps, 4);
            ps += __shfl_xor(ps, 8);
            lrow[r] = lrow[r] * alpha + ps;
            mrow[r] = mnew;
#pragma unroll
            for (int nf = 0; nf < 8; ++nf) oacc[nf][r] *= alpha;
        }

        // ---- P -> bf16 -> per-wave Ps (swizzled; private, no barrier) -----
        u16* pw = &Ps[wid][0];
#pragma unroll
        for (int nf = 0; nf < 4; ++nf)
#pragma unroll
            for (int r = 0; r < 4; ++r) {
                int prow = lk * 4 + r;
                int col = nf * 16 + lr;
                int sl = (col >> 3) ^ (prow & 7);
                pw[(prow * 8 + sl) * 8 + (col & 7)] = f2bf(sf[nf][r]);
            }

        // ---- out += P*V ---------------------------------------------------
        __builtin_amdgcn_s_setprio(1);
#pragma unroll
        for (int kp = 0; kp < 2; ++kp) {
            int sla = (kp * 4 + lk) ^ (lr & 7);
            bf16x8 pa = *(const bf16x8*)&pw[(lr * 8 + sla) * 8];
#pragma unroll
            for (int nf = 0; nf < 8; ++nf) {
                int vrow = nf * 16 + lr;
                int slv = (kp * 4 + lk) ^ (vrow & 7);
                bf16x8 vf = *(const bf16x8*)&Vs[(vrow * 8 + slv) * 8];
                oacc[nf] = __builtin_amdgcn_mfma_f32_16x16x32_bf16(pa, vf, oacc[nf], 0, 0, 0);
            }
        }
        __builtin_amdgcn_s_setprio(0);
    }

    // ---- epilogue (bf16) --------------------------------------------------
#pragma unroll
    for (int nf = 0; nf < 8; ++nf)
#pragma unroll
        for (int r = 0; r < 4; ++r) {
            int q = q0 + wid * 16 + lk * 4 + r;
            int d = nf * 16 + lr;
            ao[((size_t)(b * SEQ + q)) * (NHEAD * DHEAD) + h * DHEAD + d] =
                f2bf(oacc[nf][r] / lrow[r]);
        }
}

// ---------------------------------------------------------------------------
// Workspace map (u16 units; total 70,254,592 = 140.5 MB; 148.9 MB proven).
//   xb    [0,        8388608)   x bf16 [4096][2048]        (ao alias, later)
//   c1    [8388608, 15204352)   [4096][1664]: ckv|cq|krr|pad64
//   c2    [15204352,31981568)   [4096][4096]: kc|vv
//   c3    [31981568,44564480)   [4096][3072]: qc|qr_pre
//   qrb   [44564480,48758784)   [4096][1024]
//   krb   [48758784,49020928)   [4096][64]
//   vt    [49020928,57409536)   [2][2048][2048]
//   wcat1 [57409536,60817408)   [1664][2048] (rows 1600-1663 junk, harmless)
//   wcat2 [60817408,62914560)   [4096][512]
//   wcat3 [62914560,66060288)   [3072][1024]
//   woutT [66060288,70254592)   [2048][2048]
// Alias: ao = xb (xb dead after proj1; ao written by attn, read by final gemm).
// ---------------------------------------------------------------------------
extern "C" void kernel_launch(void* const* d_in, const int* in_sizes, int n_in,
                              void* d_out, int out_size, void* d_ws, size_t ws_size,
                              hipStream_t stream)
{
    const float* x     = (const float*)d_in[0];
    const float* w_dkv = (const float*)d_in[1];
    const float* w_uk  = (const float*)d_in[2];
    const float* w_uv  = (const float*)d_in[3];
    const float* w_dq  = (const float*)d_in[4];
    const float* w_uq  = (const float*)d_in[5];
    const float* w_qr  = (const float*)d_in[6];
    const float* w_kr  = (const float*)d_in[7];
    const float* w_out = (const float*)d_in[8];
    const float* delta = (const float*)d_in[9];
    float* out = (float*)d_out;
    u16* ws = (u16*)d_ws;

    const int M = BATCH * SEQ;   // 4096

    u16* xb    = ws;
    u16* ao    = ws;                         // alias (xb dead after proj1)
    u16* c1    = ws + 8388608;               // [4096][1664]
    u16* c2    = ws + 15204352;              // [4096][4096]
    u16* c3    = ws + 31981568;              // [4096][3072]
    u16* qrb   = ws + 44564480;              // [4096][1024]
    u16* krb   = ws + 48758784;              // [4096][64]
    u16* vt    = ws + 49020928;              // [2][2048][2048]
    u16* wcat1 = ws + 57409536;              // [1664][2048]
    u16* wcat2 = ws + 60817408;              // [4096][512]
    u16* wcat3 = ws + 62914560;              // [3072][1024]
    u16* woutT = ws + 66060288;              // [2048][2048]

    dim3 blk(256);

    // ---- converts / weight transposes (bf16) ------------------------------
    convert_bf16<<<dim3(8192), blk, 0, stream>>>(x, xb, M * DMODEL);
    transpose_f32_bf16<<<dim3(8, 32), blk, 0, stream>>>(w_dkv, wcat1, DMODEL, DCKV);                  // rows 0-511
    transpose_f32_bf16<<<dim3(16, 32), blk, 0, stream>>>(w_dq, wcat1 + 512 * 2048, DMODEL, DCQ);      // rows 512-1535
    transpose_f32_bf16<<<dim3(1, 32), blk, 0, stream>>>(w_kr, wcat1 + 1536 * 2048, DMODEL, DROPE);    // rows 1536-1599
    transpose_f32_bf16<<<dim3(32, 8), blk, 0, stream>>>(w_uk, wcat2, DCKV, 2048);                     // rows 0-2047
    transpose_f32_bf16<<<dim3(32, 8), blk, 0, stream>>>(w_uv, wcat2 + 2048 * 512, DCKV, 2048);        // rows 2048-4095
    transpose_f32_bf16<<<dim3(32, 16), blk, 0, stream>>>(w_uq, wcat3, DCQ, 2048);                     // rows 0-2047
    transpose_f32_bf16<<<dim3(16, 16), blk, 0, stream>>>(w_qr, wcat3 + 2048 * 1024, DCQ, 1024);       // rows 2048-3071
    transpose_f32_bf16<<<dim3(32, 32), blk, 0, stream>>>(w_out, woutT, 2048, DMODEL);

    // ---- merged projection GEMMs ------------------------------------------
    // proj1: x @ [w_dkv | w_dq | w_kr]  -> c1 [4096][1664]
    gemm_bf16<1><<<dim3(13, 32), blk, 0, stream>>>(xb, wcat1, c1, M, 1664, DMODEL, 2048, 2048, 1664);
    // proj2: ckv @ [w_uk | w_uv]        -> c2 [4096][4096]
    gemm_bf16<1><<<dim3(32, 32), blk, 0, stream>>>(c1, wcat2, c2, M, 4096, DCKV, 1664, 512, 4096);
    // proj3: cq @ [w_uq | w_qr]         -> c3 [4096][3072]
    gemm_bf16<1><<<dim3(24, 32), blk, 0, stream>>>(c1 + 512, wcat3, c3, M, 3072, DCQ, 1664, 1024, 3072);

    // ---- rope (bf16 in, bf16 out) -----------------------------------------
    pope_b16<<<dim3(8192), blk, 0, stream>>>(c3 + 2048, 3072, qrb, 1024, delta, NHEAD);
    pope_b16<<<dim3(512), blk, 0, stream>>>(c1 + 1536, 1664, krb, 64, delta, 1);

    // ---- V -> V^T per batch (vv = c2 cols 2048-4095) ----------------------
    transpose_b16<<<dim3(32, 32, BATCH), blk, 0, stream>>>(c2 + 2048, vt, SEQ, 2048, 4096,
                                                           (size_t)SEQ * 4096, (size_t)2048 * 2048);

    // ---- attention (bf16 out) ---------------------------------------------
    attn_mfma<<<dim3(SEQ / 64, BATCH * NHEAD), blk, 0, stream>>>(c3, qrb, c2, krb, vt, ao);

    // ---- output projection (fp32 out) -------------------------------------
    gemm_bf16<0><<<dim3(16, 32), blk, 0, stream>>>(ao, woutT, out, M, DMODEL, 2048, 2048, 2048, 2048);
}